// Round 11
// baseline (25067.851 us; speedup 1.0000x reference)
//
#include <hip/hip_runtime.h>
#include <cstddef>

#define B_SZ   16
#define T_SZ   4096
#define D_SZ   512
#define NSLOT  64
#define NW     16          // workgroups (d-slices) per batch
#define RPW    32          // rows per WG slice (D_SZ / NW)
#define TP     36          // LDS tape row stride (floats; 144B, 16B-aligned)
#define SCALE  0.044194173824159216f   // 1/sqrt(512)

// ---- cross-WG exchange: self-tagged (float,tag) 8B pairs (relaxed agent
// ---- atomics, no fences — see R5). Producers zero their own slots at start;
// ---- equality-poll on the tag is replay-safe (monotone per-address history).
// ---- Overwrite-safety: a producer republishes a slot (tag t+2) only after an
// ---- exchange that proves every consumer already read tag t+1 (q rendezvous).
__device__ __align__(8) unsigned long long g_pb[B_SZ * NW * NSLOT]; // score partials [b][w][slot]
__device__ __align__(8) unsigned long long g_hb[B_SZ * D_SZ];      // h slices, flat [b][d]
__device__ __align__(8) unsigned long long g_q [B_SZ * NW * 2];    // per-wave quadratic partials

#define AL(p)    __hip_atomic_load((p),  __ATOMIC_RELAXED, __HIP_MEMORY_SCOPE_AGENT)
#define AS(p,v)  __hip_atomic_store((p), (v), __ATOMIC_RELAXED, __HIP_MEMORY_SCOPE_AGENT)

__device__ __forceinline__ unsigned long long pk(float v, unsigned tag) {
    return ((unsigned long long)tag << 32) | (unsigned long long)__float_as_uint(v);
}
__device__ __forceinline__ float lo(unsigned long long v) {
    return __uint_as_float((unsigned)v);
}

// ---------------------------------------------------------------------------
// Kernel 1: xw[b][t][d] = x[b][t][:] . W_x[d][:] + b_h[d]  -> h_work_out region
// ---------------------------------------------------------------------------
__global__ __launch_bounds__(256)
void xw_gemm_kernel(const float* __restrict__ X, const float* __restrict__ Wx,
                    const float* __restrict__ bh, float* __restrict__ out)
{
    __shared__ float As[16][68];
    __shared__ float Bs[16][68];
    const int m0 = blockIdx.x * 64;
    const int n0 = blockIdx.y * 64;
    const int tid = threadIdx.x;
    const int tr = tid >> 4, tc = tid & 15;
    const int lrow = tid >> 2;
    const int lkk  = (tid & 3) * 4;

    float acc[4][4] = {};

    for (int k0 = 0; k0 < D_SZ; k0 += 16) {
        float4 av = *(const float4*)(X  + (size_t)(m0 + lrow) * D_SZ + k0 + lkk);
        float4 bv = *(const float4*)(Wx + (size_t)(n0 + lrow) * D_SZ + k0 + lkk);
        As[lkk+0][lrow] = av.x; As[lkk+1][lrow] = av.y;
        As[lkk+2][lrow] = av.z; As[lkk+3][lrow] = av.w;
        Bs[lkk+0][lrow] = bv.x; Bs[lkk+1][lrow] = bv.y;
        Bs[lkk+2][lrow] = bv.z; Bs[lkk+3][lrow] = bv.w;
        __syncthreads();
        #pragma unroll
        for (int kk = 0; kk < 16; ++kk) {
            float a[4], bq[4];
            #pragma unroll
            for (int i = 0; i < 4; ++i) a[i] = As[kk][tr*4+i];
            #pragma unroll
            for (int j = 0; j < 4; ++j) bq[j] = Bs[kk][tc*4+j];
            #pragma unroll
            for (int i = 0; i < 4; ++i)
                #pragma unroll
                for (int j = 0; j < 4; ++j)
                    acc[i][j] = fmaf(a[i], bq[j], acc[i][j]);
        }
        __syncthreads();
    }
    #pragma unroll
    for (int i = 0; i < 4; ++i) {
        const int m = m0 + tr*4 + i;
        const int n = n0 + tc*4;
        float4 o;
        o.x = acc[i][0] + bh[n+0];
        o.y = acc[i][1] + bh[n+1];
        o.z = acc[i][2] + bh[n+2];
        o.w = acc[i][3] + bh[n+3];
        *(float4*)(out + (size_t)m * D_SZ + n) = o;
    }
}

// ---------------------------------------------------------------------------
// Kernel 2: wave-specialized single-bundle recurrence.
//  P0 (all): poll h only.  P1: waves 2-3 fused matvec (+in-reg q partial),
//  waves 0-1 poll score partials -> scr.  q published after b2.  P2 softmax
//  (wave0, masked slot).  P3 rpA.  P4 (tid<32): q poll, combine, tanh,
//  publish h.  P5 (all): publish next-step score partials.
// ---------------------------------------------------------------------------
__global__ __launch_bounds__(256, 1)
void recurrence_mw(const float* __restrict__ tape0, const float* __restrict__ h0,
                   const float* __restrict__ W_h, const float* __restrict__ W_w,
                   float* __restrict__ out)
{
    __shared__ __align__(16) float tp[NSLOT][TP];  // tape d-slice [slot][32]
    __shared__ __align__(16) float hh[D_SZ];       // full current h
    __shared__ __align__(16) float hno[RPW];       // own h_new slice
    __shared__ float scr[NSLOT];                   // total scores (scaled)
    __shared__ float es[NSLOT];                    // exp(score - m63)
    __shared__ float zmv[RPW];
    __shared__ float rp8[8][RPW];
    __shared__ float sml[2];                       // m63, S63

    const int blk = blockIdx.x;
    const int xcd = blk & 7;
    const int jj0 = blk >> 3;
    const int b   = xcd * 2 + (jj0 & 1);
    const int w   = jj0 >> 1;
    const int R0  = w * RPW;
    const int tid = threadIdx.x;
    const int fb  = b * NW;
    const int sA  = tid >> 2, qA = tid & 3;    // P5: 4 threads per slot
    const int sg  = tid >> 5, jB = tid & 31;   // P3: 8 slot-groups

    // ---- zero own pair slots (replay safety; same-producer-thread ordering) ----
    if (tid < NSLOT) AS(&g_pb[((size_t)fb + w) * NSLOT + tid], 0ULL);
    if (tid < RPW)   AS(&g_hb[(size_t)b * D_SZ + R0 + tid], 0ULL);
    if (tid == 128)  AS(&g_q[((size_t)fb + w) * 2 + 0], 0ULL);
    if (tid == 192)  AS(&g_q[((size_t)fb + w) * 2 + 1], 0ULL);

    // ---- stage tape d-slice + full h0 ----
    for (int i = tid; i < NSLOT * RPW; i += 256) {
        const int s = i >> 5, j = i & 31;
        tp[s][j] = tape0[((size_t)b * NSLOT + s) * D_SZ + R0 + j];
    }
    for (int i = tid; i < D_SZ; i += 256) hh[i] = h0[(size_t)b * D_SZ + i];
    __syncthreads();

    float* outb = out + (size_t)b * T_SZ * D_SZ;

    // ---- prologue: publish bundle serving step 0 (tag 1) ----
    if (tid < RPW) {
        hno[tid] = hh[R0 + tid];
        AS(&g_hb[(size_t)b * D_SZ + R0 + tid], pk(hh[R0 + tid], 1u));
    }
    __syncthreads();
    {
        const float* trow = &tp[sA][8 * qA];
        float4 t0 = *(const float4*)trow;
        float4 t1 = *(const float4*)(trow + 4);
        float4 h0v = *(const float4*)&hno[8 * qA];
        float4 h1v = *(const float4*)&hno[8 * qA + 4];
        float pp = t0.x*h0v.x + t0.y*h0v.y + t0.z*h0v.z + t0.w*h0v.w
                 + t1.x*h1v.x + t1.y*h1v.y + t1.z*h1v.z + t1.w*h1v.w;
        pp += __shfl_xor(pp, 1);
        pp += __shfl_xor(pp, 2);
        if (qA == 0) AS(&g_pb[((size_t)fb + w) * NSLOT + sA], pk(pp, 1u));
    }

    for (int t = 0; t < T_SZ; ++t) {
        const unsigned tgB = (unsigned)(t + 1);
        const int sp = (t - 1) & 63;   // slot pending update (valid when t>0)

        // ---- P0: xw prefetch (issued first), then poll h only ----
        float xwv = 0.f;
        if (tid < RPW) xwv = outb[(size_t)t * D_SZ + R0 + tid];
        {
            const unsigned long long* hb = &g_hb[(size_t)b * D_SZ + 2 * tid];
            unsigned long long v0, v1;
            for (;;) {
                v0 = AL(hb); v1 = AL(hb + 1);
                if ((unsigned)(v0 >> 32) == tgB && (unsigned)(v1 >> 32) == tgB) break;
            }
            hh[2 * tid]     = lo(v0);
            hh[2 * tid + 1] = lo(v1);
        }
        __syncthreads();   // b1

        // ---- P1: waves 2-3 matvec; waves 0-1 poll score partials ----
        float qwave = 0.f;
        if (tid >= 128) {
            const int t1  = tid - 128;       // 0..127
            const int rr  = t1 >> 3;         // 0..15
            const int sj8 = t1 & 7;          // 8 k-lanes
            const float* whA = W_h + (size_t)(R0 + rr)      * D_SZ;
            const float* whB = W_h + (size_t)(R0 + rr + 16) * D_SZ;
            const float* wwA = W_w + (size_t)(R0 + rr)      * D_SZ;
            const float* wwB = W_w + (size_t)(R0 + rr + 16) * D_SZ;
            float z0 = 0.f, z1 = 0.f, y0 = 0.f, y1 = 0.f;
            #pragma unroll
            for (int i = 0; i < 16; ++i) {
                const int col = 4 * sj8 + 32 * i;
                float4 hr = *(const float4*)&hh[col];
                float4 a0 = *(const float4*)(whA + col);
                float4 a1 = *(const float4*)(whB + col);
                float4 b0 = *(const float4*)(wwA + col);
                float4 b1v = *(const float4*)(wwB + col);
                z0 = fmaf(a0.x, hr.x, z0); z0 = fmaf(a0.y, hr.y, z0);
                z0 = fmaf(a0.z, hr.z, z0); z0 = fmaf(a0.w, hr.w, z0);
                z1 = fmaf(a1.x, hr.x, z1); z1 = fmaf(a1.y, hr.y, z1);
                z1 = fmaf(a1.z, hr.z, z1); z1 = fmaf(a1.w, hr.w, z1);
                y0 = fmaf(b0.x, hr.x, y0); y0 = fmaf(b0.y, hr.y, y0);
                y0 = fmaf(b0.z, hr.z, y0); y0 = fmaf(b0.w, hr.w, y0);
                y1 = fmaf(b1v.x, hr.x, y1); y1 = fmaf(b1v.y, hr.y, y1);
                y1 = fmaf(b1v.z, hr.z, y1); y1 = fmaf(b1v.w, hr.w, y1);
            }
            #pragma unroll
            for (int o = 1; o <= 4; o <<= 1) {
                z0 += __shfl_xor(z0, o); z1 += __shfl_xor(z1, o);
                y0 += __shfl_xor(y0, o); y1 += __shfl_xor(y1, o);
            }
            float c = 0.f;
            if (sj8 == 0) {
                zmv[rr]      = z0;
                zmv[rr + 16] = z1;
                if (t > 0) { tp[sp][rr] = y0; tp[sp][rr + 16] = y1; }
                c = y0 * hh[R0 + rr] + y1 * hh[R0 + rr + 16];
            }
            c += __shfl_xor(c, 8);
            c += __shfl_xor(c, 16);
            c += __shfl_xor(c, 32);
            qwave = c;                      // lane0 of each wave holds wave sum
        } else {
            const int s  = tid >> 1;        // slot 0..63
            const int hf = tid & 1;         // which 8 WGs
            const unsigned long long* pb = &g_pb[((size_t)fb + hf * 8) * NSLOT + s];
            unsigned long long p[8];
            for (;;) {
                bool ok = true;
                #pragma unroll
                for (int k = 0; k < 8; ++k) {
                    p[k] = AL(pb + (size_t)k * NSLOT);
                    ok &= ((unsigned)(p[k] >> 32) == tgB);
                }
                if (ok) break;
            }
            float ls = 0.f;
            #pragma unroll
            for (int k = 0; k < 8; ++k) ls += lo(p[k]);
            ls += __shfl_xor(ls, 1);
            if (hf == 0) scr[s] = ls * SCALE;
        }
        __syncthreads();   // b2

        // ---- q publish (after b2: proves this WG's partials-poll is done) ----
        if (tid == 128) AS(&g_q[((size_t)fb + w) * 2 + 0], pk(qwave, tgB));
        if (tid == 192) AS(&g_q[((size_t)fb + w) * 2 + 1], pk(qwave, tgB));

        // ---- P2: softmax over 63 slots (wave 0; pending slot masked) ----
        if (tid < 64) {
            const float v = (t > 0 && tid == sp) ? -3.0e38f : scr[tid];
            float m = v;
            #pragma unroll
            for (int o = 32; o; o >>= 1) m = fmaxf(m, __shfl_xor(m, o));
            const float e = __expf(v - m);
            float s = e;
            #pragma unroll
            for (int o = 32; o; o >>= 1) s += __shfl_xor(s, o);
            es[tid] = e;
            if (tid == 0) { sml[0] = m; sml[1] = s; }
        }
        __syncthreads();   // b3

        // ---- P3: rpA partials (es[sp]==0 excludes the pending slot) ----
        {
            float acc = 0.f;
            #pragma unroll
            for (int s8 = 0; s8 < 8; ++s8)
                acc = fmaf(es[sg * 8 + s8], tp[sg * 8 + s8][jB], acc);
            rp8[sg][jB] = acc;
        }
        __syncthreads();   // b4

        // ---- P4: combine (tid<32): q poll (rendezvous every step), tanh, publish h ----
        if (tid < RPW) {
            const float rr8 = rp8[0][tid] + rp8[1][tid] + rp8[2][tid] + rp8[3][tid]
                            + rp8[4][tid] + rp8[5][tid] + rp8[6][tid] + rp8[7][tid];
            const unsigned long long* qp_ = &g_q[((size_t)fb + (tid & 15)) * 2];
            unsigned long long q0, q1;
            for (;;) {
                q0 = AL(qp_); q1 = AL(qp_ + 1);
                if ((unsigned)(q0 >> 32) == tgB && (unsigned)(q1 >> 32) == tgB) break;
            }
            float rd;
            if (t > 0) {
                float qs = lo(q0) + lo(q1);
                qs += __shfl_xor(qs, 1); qs += __shfl_xor(qs, 2);
                qs += __shfl_xor(qs, 4); qs += __shfl_xor(qs, 8);
                const float esig = __expf(qs * SCALE - sml[0]);
                rd = (rr8 + esig * tp[sp][tid]) / (sml[1] + esig);
            } else {
                rd = rr8 / sml[1];
            }
            const float hn = tanhf(zmv[tid] + rd + xwv);
            AS(&g_hb[(size_t)b * D_SZ + R0 + tid], pk(hn, (unsigned)(t + 2)));
            hno[tid] = hn;
            outb[(size_t)t * D_SZ + R0 + tid] = hn;
        }
        __syncthreads();   // b5

        // ---- P5: score partials for step t+1 (all 64 slots; consumer masks) ----
        {
            const float* trow = &tp[sA][8 * qA];
            float4 t0 = *(const float4*)trow;
            float4 t1 = *(const float4*)(trow + 4);
            float4 h0v = *(const float4*)&hno[8 * qA];
            float4 h1v = *(const float4*)&hno[8 * qA + 4];
            float pp = t0.x*h0v.x + t0.y*h0v.y + t0.z*h0v.z + t0.w*h0v.w
                     + t1.x*h1v.x + t1.y*h1v.y + t1.z*h1v.z + t1.w*h1v.w;
            pp += __shfl_xor(pp, 1);
            pp += __shfl_xor(pp, 2);
            if (qA == 0) AS(&g_pb[((size_t)fb + w) * NSLOT + sA], pk(pp, (unsigned)(t + 2)));
        }
        // no trailing barrier: next P0 writes hh only (disjoint from P5's reads)
    }

    // ---- epilogue: gather h_T, final slot-63 update, write tape + last h ----
    {
        const unsigned long long* hb = &g_hb[(size_t)b * D_SZ + 2 * tid];
        const unsigned tgF = (unsigned)(T_SZ + 1);
        unsigned long long v0, v1;
        for (;;) {
            v0 = AL(hb); v1 = AL(hb + 1);
            if ((unsigned)(v0 >> 32) == tgF && (unsigned)(v1 >> 32) == tgF) break;
        }
        hh[2 * tid]     = lo(v0);
        hh[2 * tid + 1] = lo(v1);
    }
    __syncthreads();
    if (tid >= 128) {   // final tape write: slot 63 <- W_w . h_T
        const int t1  = tid - 128;
        const int rr  = t1 >> 3;
        const int sj8 = t1 & 7;
        const float* wwA = W_w + (size_t)(R0 + rr)      * D_SZ;
        const float* wwB = W_w + (size_t)(R0 + rr + 16) * D_SZ;
        float y0 = 0.f, y1 = 0.f;
        #pragma unroll
        for (int i = 0; i < 16; ++i) {
            const int col = 4 * sj8 + 32 * i;
            float4 hr = *(const float4*)&hh[col];
            float4 b0 = *(const float4*)(wwA + col);
            float4 b1v = *(const float4*)(wwB + col);
            y0 = fmaf(b0.x, hr.x, y0); y0 = fmaf(b0.y, hr.y, y0);
            y0 = fmaf(b0.z, hr.z, y0); y0 = fmaf(b0.w, hr.w, y0);
            y1 = fmaf(b1v.x, hr.x, y1); y1 = fmaf(b1v.y, hr.y, y1);
            y1 = fmaf(b1v.z, hr.z, y1); y1 = fmaf(b1v.w, hr.w, y1);
        }
        #pragma unroll
        for (int o = 1; o <= 4; o <<= 1) { y0 += __shfl_xor(y0, o); y1 += __shfl_xor(y1, o); }
        if (sj8 == 0) { tp[63][rr] = y0; tp[63][rr + 16] = y1; }
    }
    __syncthreads();
    float* tout = out + (size_t)B_SZ * T_SZ * D_SZ + (size_t)b * NSLOT * D_SZ;
    for (int i = tid; i < NSLOT * RPW; i += 256) {
        const int s = i >> 5, j = i & 31;
        tout[(size_t)s * D_SZ + R0 + j] = tp[s][j];
    }
    if (w == 0) {
        float* lout = out + (size_t)B_SZ * T_SZ * D_SZ
                          + (size_t)B_SZ * NSLOT * D_SZ + (size_t)b * D_SZ;
        for (int i = tid; i < D_SZ; i += 256) lout[i] = hh[i];
    }
}

// ---------------------------------------------------------------------------
extern "C" void kernel_launch(void* const* d_in, const int* in_sizes, int n_in,
                              void* d_out, int out_size, void* d_ws, size_t ws_size,
                              hipStream_t stream)
{
    const float* x_seq   = (const float*)d_in[0];
    const float* h_tape  = (const float*)d_in[1];
    const float* h_work  = (const float*)d_in[2];
    const float* W_h     = (const float*)d_in[3];
    const float* W_x     = (const float*)d_in[4];
    const float* b_h     = (const float*)d_in[5];
    const float* W_write = (const float*)d_in[6];
    float* out = (float*)d_out;

    dim3 g1(T_SZ * B_SZ / 64, D_SZ / 64);
    xw_gemm_kernel<<<g1, 256, 0, stream>>>(x_seq, W_x, b_h, out);

    recurrence_mw<<<B_SZ * NW, 256, 0, stream>>>(h_tape, h_work, W_h, W_write, out);
}

// Round 12
// 21813.268 us; speedup vs baseline: 1.1492x; 1.1492x over previous
//
#include <hip/hip_runtime.h>
#include <cstddef>

#define B_SZ   16
#define T_SZ   4096
#define D_SZ   512
#define NSLOT  64
#define NW     16          // workgroups (d-slices) per batch
#define RPW    32          // rows per WG slice (D_SZ / NW)
#define TP     36          // LDS tape row stride (floats; 144B, 16B-aligned)
#define SCALE  0.044194173824159216f   // 1/sqrt(512)

// ---- cross-WG exchange: self-tagged (float,tag) 8B pairs.
// SAFE buffers: relaxed agent-scope atomics (MALL, always correct).
// FAST mirrors: plain stores + sc0 loads — valid rendezvous only when producer
// and consumer share an XCD L2 (blk%8 heuristic). Consumers use budgeted fast
// polls with permanent fallback to the safe poll, so correctness NEVER depends
// on the mapping (G16). Producers always dual-publish.
__device__ __align__(8) unsigned long long g_pb[B_SZ * NW * NSLOT];  // safe partials
__device__ __align__(8) unsigned long long g_hb[B_SZ * D_SZ];        // safe h
__device__ __align__(8) unsigned long long g_q [B_SZ * NW];          // safe q
__device__ __align__(8) unsigned long long g_pbF[B_SZ * NW * NSLOT]; // fast partials
__device__ __align__(8) unsigned long long g_hbF[B_SZ * D_SZ];       // fast h
__device__ __align__(8) unsigned long long g_qF [B_SZ * NW];         // fast q

#define AL(p)    __hip_atomic_load((p),  __ATOMIC_RELAXED, __HIP_MEMORY_SCOPE_AGENT)
#define AS(p,v)  __hip_atomic_store((p), (v), __ATOMIC_RELAXED, __HIP_MEMORY_SCOPE_AGENT)

__device__ __forceinline__ unsigned long long pk(float v, unsigned tag) {
    return ((unsigned long long)tag << 32) | (unsigned long long)__float_as_uint(v);
}
__device__ __forceinline__ float lo(unsigned long long v) {
    return __uint_as_float((unsigned)v);
}
// fast-mirror store: plain 8B store, write-through L1 -> local L2
__device__ __forceinline__ void FS(unsigned long long* p, unsigned long long v) {
    asm volatile("global_store_dwordx2 %0, %1, off" :: "v"(p), "v"(v) : "memory");
}
// fast-mirror load: sc0 = bypass L1, hit L2 (NOT sc1 -> stays on-XCD)
__device__ __forceinline__ unsigned long long FL(const unsigned long long* p) {
    unsigned long long v;
    asm volatile("global_load_dwordx2 %0, %1, off sc0" : "=v"(v) : "v"(p) : "memory");
    return v;
}
// rule-18 fence: drain loads, then stop the scheduler moving uses above it
#define VM0_SB() do { asm volatile("s_waitcnt vmcnt(0)" ::: "memory"); \
                      __builtin_amdgcn_sched_barrier(0); } while (0)

// ---------------------------------------------------------------------------
// Kernel 1: xw[b][t][d] = x[b][t][:] . W_x[d][:] + b_h[d]  -> h_work_out region
// ---------------------------------------------------------------------------
__global__ __launch_bounds__(256)
void xw_gemm_kernel(const float* __restrict__ X, const float* __restrict__ Wx,
                    const float* __restrict__ bh, float* __restrict__ out)
{
    __shared__ float As[16][68];
    __shared__ float Bs[16][68];
    const int m0 = blockIdx.x * 64;
    const int n0 = blockIdx.y * 64;
    const int tid = threadIdx.x;
    const int tr = tid >> 4, tc = tid & 15;
    const int lrow = tid >> 2;
    const int lkk  = (tid & 3) * 4;

    float acc[4][4] = {};

    for (int k0 = 0; k0 < D_SZ; k0 += 16) {
        float4 av = *(const float4*)(X  + (size_t)(m0 + lrow) * D_SZ + k0 + lkk);
        float4 bv = *(const float4*)(Wx + (size_t)(n0 + lrow) * D_SZ + k0 + lkk);
        As[lkk+0][lrow] = av.x; As[lkk+1][lrow] = av.y;
        As[lkk+2][lrow] = av.z; As[lkk+3][lrow] = av.w;
        Bs[lkk+0][lrow] = bv.x; Bs[lkk+1][lrow] = bv.y;
        Bs[lkk+2][lrow] = bv.z; Bs[lkk+3][lrow] = bv.w;
        __syncthreads();
        #pragma unroll
        for (int kk = 0; kk < 16; ++kk) {
            float a[4], bq[4];
            #pragma unroll
            for (int i = 0; i < 4; ++i) a[i] = As[kk][tr*4+i];
            #pragma unroll
            for (int j = 0; j < 4; ++j) bq[j] = Bs[kk][tc*4+j];
            #pragma unroll
            for (int i = 0; i < 4; ++i)
                #pragma unroll
                for (int j = 0; j < 4; ++j)
                    acc[i][j] = fmaf(a[i], bq[j], acc[i][j]);
        }
        __syncthreads();
    }
    #pragma unroll
    for (int i = 0; i < 4; ++i) {
        const int m = m0 + tr*4 + i;
        const int n = n0 + tc*4;
        float4 o;
        o.x = acc[i][0] + bh[n+0];
        o.y = acc[i][1] + bh[n+1];
        o.z = acc[i][2] + bh[n+2];
        o.w = acc[i][3] + bh[n+3];
        *(float4*)(out + (size_t)m * D_SZ + n) = o;
    }
}

// ---------------------------------------------------------------------------
// Kernel 2: R7 structure + fast-path exchange.
// ---------------------------------------------------------------------------
__global__ __launch_bounds__(256, 1)
void recurrence_mw(const float* __restrict__ tape0, const float* __restrict__ h0,
                   const float* __restrict__ W_h, const float* __restrict__ W_w,
                   float* __restrict__ out)
{
    __shared__ __align__(16) float tp[NSLOT][TP];
    __shared__ __align__(16) float hh[D_SZ];
    __shared__ __align__(16) float hno[RPW];
    __shared__ float scr[NSLOT];
    __shared__ float es[NSLOT];
    __shared__ float zmv[RPW];
    __shared__ float rp8[8][RPW];
    __shared__ float sml[2];

    const int blk = blockIdx.x;
    const int xcd = blk & 7;
    const int jj0 = blk >> 3;
    const int b   = xcd * 2 + (jj0 & 1);
    const int w   = jj0 >> 1;
    const int R0  = w * RPW;
    const int tid = threadIdx.x;
    const int fb  = b * NW;
    const int g16 = tid >> 4, sj = tid & 15;
    const int sA  = tid >> 2, qA = tid & 3;
    const int sg  = tid >> 5, jB = tid & 31;

    // ---- zero own pair slots in BOTH buffers (replay safety) ----
    if (tid < NSLOT) {
        AS(&g_pb [((size_t)fb + w) * NSLOT + tid], 0ULL);
        FS(&g_pbF[((size_t)fb + w) * NSLOT + tid], 0ULL);
    }
    if (tid < RPW) {
        AS(&g_hb [(size_t)b * D_SZ + R0 + tid], 0ULL);
        FS(&g_hbF[(size_t)b * D_SZ + R0 + tid], 0ULL);
    }
    if (tid == 0) { AS(&g_q[fb + w], 0ULL); FS(&g_qF[fb + w], 0ULL); }

    // ---- stage tape d-slice + full h0 ----
    for (int i = tid; i < NSLOT * RPW; i += 256) {
        const int s = i >> 5, j = i & 31;
        tp[s][j] = tape0[((size_t)b * NSLOT + s) * D_SZ + R0 + j];
    }
    for (int i = tid; i < D_SZ; i += 256) hh[i] = h0[(size_t)b * D_SZ + i];
    __syncthreads();

    float* outb = out + (size_t)b * T_SZ * D_SZ;

    // ---- prologue: publish bundle serving step 0 (tag 1) ----
    if (tid < RPW) {
        hno[tid] = hh[R0 + tid];
        const unsigned long long v = pk(hh[R0 + tid], 1u);
        FS(&g_hbF[(size_t)b * D_SZ + R0 + tid], v);
        AS(&g_hb [(size_t)b * D_SZ + R0 + tid], v);
    }
    __syncthreads();
    {
        const float* trow = &tp[sA][8 * qA];
        float4 t0 = *(const float4*)trow;
        float4 t1 = *(const float4*)(trow + 4);
        float4 h0v = *(const float4*)&hno[8 * qA];
        float4 h1v = *(const float4*)&hno[8 * qA + 4];
        float pp = t0.x*h0v.x + t0.y*h0v.y + t0.z*h0v.z + t0.w*h0v.w
                 + t1.x*h1v.x + t1.y*h1v.y + t1.z*h1v.z + t1.w*h1v.w;
        pp += __shfl_xor(pp, 1);
        pp += __shfl_xor(pp, 2);
        if (qA == 0) {
            const unsigned long long v = pk(pp, 1u);
            FS(&g_pbF[((size_t)fb + w) * NSLOT + sA], v);
            AS(&g_pb [((size_t)fb + w) * NSLOT + sA], v);
        }
    }

    bool fast0 = true, fastq = true;   // per-thread fast-path memo

    for (int t = 0; t < T_SZ; ++t) {
        const unsigned tgB = (unsigned)(t + 1);
        const int sp = (t - 1) & 63;

        // ---- P0: xw prefetch, then poll partials(4)+h(2) — fast else safe ----
        float xwv = 0.f;
        if (tid < RPW) xwv = outb[(size_t)t * D_SZ + R0 + tid];
        {
            const unsigned long long* pbS = &g_pb [((size_t)fb + qA * 4) * NSLOT + sA];
            const unsigned long long* hbS = &g_hb [(size_t)b * D_SZ + 2 * tid];
            const unsigned long long* pbF = &g_pbF[((size_t)fb + qA * 4) * NSLOT + sA];
            const unsigned long long* hbF = &g_hbF[(size_t)b * D_SZ + 2 * tid];
            unsigned long long p0, p1, p2, p3, v0, v1;
            bool got = false;
            if (fast0) {
                int budget = (t == 0) ? 1200 : 200;
                for (;;) {
                    p0 = FL(pbF);             p1 = FL(pbF + NSLOT);
                    p2 = FL(pbF + 2 * NSLOT); p3 = FL(pbF + 3 * NSLOT);
                    v0 = FL(hbF);             v1 = FL(hbF + 1);
                    VM0_SB();
                    if ((unsigned)(p0 >> 32) == tgB && (unsigned)(p1 >> 32) == tgB &&
                        (unsigned)(p2 >> 32) == tgB && (unsigned)(p3 >> 32) == tgB &&
                        (unsigned)(v0 >> 32) == tgB && (unsigned)(v1 >> 32) == tgB) {
                        got = true; break;
                    }
                    if (--budget <= 0) break;
                }
                if (!got) fast0 = false;
            }
            if (!got) {
                for (;;) {
                    p0 = AL(pbS);              p1 = AL(pbS + NSLOT);
                    p2 = AL(pbS + 2 * NSLOT);  p3 = AL(pbS + 3 * NSLOT);
                    v0 = AL(hbS);              v1 = AL(hbS + 1);
                    if ((unsigned)(p0 >> 32) == tgB && (unsigned)(p1 >> 32) == tgB &&
                        (unsigned)(p2 >> 32) == tgB && (unsigned)(p3 >> 32) == tgB &&
                        (unsigned)(v0 >> 32) == tgB && (unsigned)(v1 >> 32) == tgB) break;
                    __builtin_amdgcn_s_sleep(1);
                }
            }
            float s4 = lo(p0) + lo(p1) + lo(p2) + lo(p3);
            s4 += __shfl_xor(s4, 1);
            s4 += __shfl_xor(s4, 2);
            if (qA == 0) scr[sA] = s4 * SCALE;
            hh[2 * tid]     = lo(v0);
            hh[2 * tid + 1] = lo(v1);
        }
        __syncthreads();

        // ---- P1: fused matvec: zm (W_h) + w_vec (W_w) share one hh pass ----
        {
            float z0 = 0.f, z1 = 0.f, v0 = 0.f, v1 = 0.f;
            const float* whA = W_h + (size_t)(R0 + g16)      * D_SZ + 4 * sj;
            const float* whB = W_h + (size_t)(R0 + g16 + 16) * D_SZ + 4 * sj;
            const float* wwA = W_w + (size_t)(R0 + g16)      * D_SZ + 4 * sj;
            const float* wwB = W_w + (size_t)(R0 + g16 + 16) * D_SZ + 4 * sj;
            #pragma unroll
            for (int i = 0; i < 8; ++i) {
                float4 hr = *(const float4*)&hh[4 * sj + 64 * i];
                float4 a0 = *(const float4*)(whA + 64 * i);
                float4 a1 = *(const float4*)(whB + 64 * i);
                float4 b0 = *(const float4*)(wwA + 64 * i);
                float4 b1 = *(const float4*)(wwB + 64 * i);
                z0 = fmaf(a0.x, hr.x, z0); z0 = fmaf(a0.y, hr.y, z0);
                z0 = fmaf(a0.z, hr.z, z0); z0 = fmaf(a0.w, hr.w, z0);
                z1 = fmaf(a1.x, hr.x, z1); z1 = fmaf(a1.y, hr.y, z1);
                z1 = fmaf(a1.z, hr.z, z1); z1 = fmaf(a1.w, hr.w, z1);
                v0 = fmaf(b0.x, hr.x, v0); v0 = fmaf(b0.y, hr.y, v0);
                v0 = fmaf(b0.z, hr.z, v0); v0 = fmaf(b0.w, hr.w, v0);
                v1 = fmaf(b1.x, hr.x, v1); v1 = fmaf(b1.y, hr.y, v1);
                v1 = fmaf(b1.z, hr.z, v1); v1 = fmaf(b1.w, hr.w, v1);
            }
            #pragma unroll
            for (int o = 1; o <= 8; o <<= 1) {
                z0 += __shfl_xor(z0, o); z1 += __shfl_xor(z1, o);
                v0 += __shfl_xor(v0, o); v1 += __shfl_xor(v1, o);
            }
            if (sj == 0) {
                zmv[g16] = z0; zmv[g16 + 16] = z1;
                if (t > 0) { tp[sp][g16] = v0; tp[sp][g16 + 16] = v1; }
            }
        }
        __syncthreads();

        // ---- P2: softmax over 63 (wave0) || q compute+dual-publish (tid 64..95) ----
        if (tid < 64) {
            const float v = (t > 0 && tid == sp) ? -3.0e38f : scr[tid];
            float m = v;
            #pragma unroll
            for (int o = 32; o; o >>= 1) m = fmaxf(m, __shfl_xor(m, o));
            const float e = __expf(v - m);
            float s = e;
            #pragma unroll
            for (int o = 32; o; o >>= 1) s += __shfl_xor(s, o);
            es[tid] = e;
            if (tid == 0) { sml[0] = m; sml[1] = s; }
        } else if (tid < 96 && t > 0) {
            const int ld = tid - 64;
            float qp = tp[sp][ld] * hh[R0 + ld];
            #pragma unroll
            for (int o = 1; o <= 16; o <<= 1) qp += __shfl_xor(qp, o);
            if (ld == 0) {
                const unsigned long long v = pk(qp, tgB);
                FS(&g_qF[fb + w], v);
                AS(&g_q [fb + w], v);
            }
        }
        __syncthreads();

        // ---- P3: rpA partials ----
        {
            float acc = 0.f;
            #pragma unroll
            for (int s8 = 0; s8 < 8; ++s8)
                acc = fmaf(es[sg * 8 + s8], tp[sg * 8 + s8][jB], acc);
            rp8[sg][jB] = acc;
        }
        __syncthreads();

        // ---- P4: combine (tid<32): q poll (fast else safe), tanh, publish h ----
        if (tid < RPW) {
            const float rr = rp8[0][tid] + rp8[1][tid] + rp8[2][tid] + rp8[3][tid]
                           + rp8[4][tid] + rp8[5][tid] + rp8[6][tid] + rp8[7][tid];
            float rd;
            if (t > 0) {
                const unsigned long long* qS = &g_q [fb + (tid & 15)];
                const unsigned long long* qF = &g_qF[fb + (tid & 15)];
                unsigned long long qv;
                bool got = false;
                if (fastq) {
                    int budget = (t == 1) ? 1200 : 200;
                    for (;;) {
                        qv = FL(qF);
                        VM0_SB();
                        if ((unsigned)(qv >> 32) == tgB) { got = true; break; }
                        if (--budget <= 0) break;
                    }
                    if (!got) fastq = false;
                }
                if (!got) {
                    for (;;) {
                        qv = AL(qS);
                        if ((unsigned)(qv >> 32) == tgB) break;
                        __builtin_amdgcn_s_sleep(1);
                    }
                }
                float qs = lo(qv);
                qs += __shfl_xor(qs, 1); qs += __shfl_xor(qs, 2);
                qs += __shfl_xor(qs, 4); qs += __shfl_xor(qs, 8);
                const float esig = __expf(qs * SCALE - sml[0]);
                rd = (rr + esig * tp[sp][tid]) / (sml[1] + esig);
            } else {
                rd = rr / sml[1];
            }
            const float hn = tanhf(zmv[tid] + rd + xwv);
            outb[(size_t)t * D_SZ + R0 + tid] = hn;
            const unsigned long long v = pk(hn, (unsigned)(t + 2));
            FS(&g_hbF[(size_t)b * D_SZ + R0 + tid], v);
            AS(&g_hb [(size_t)b * D_SZ + R0 + tid], v);
            hno[tid] = hn;
        }
        __syncthreads();

        // ---- P5: score partials for step t+1 (dual-publish) ----
        {
            const float* trow = &tp[sA][8 * qA];
            float4 t0 = *(const float4*)trow;
            float4 t1 = *(const float4*)(trow + 4);
            float4 h0v = *(const float4*)&hno[8 * qA];
            float4 h1v = *(const float4*)&hno[8 * qA + 4];
            float pp = t0.x*h0v.x + t0.y*h0v.y + t0.z*h0v.z + t0.w*h0v.w
                     + t1.x*h1v.x + t1.y*h1v.y + t1.z*h1v.z + t1.w*h1v.w;
            pp += __shfl_xor(pp, 1);
            pp += __shfl_xor(pp, 2);
            if (qA == 0) {
                const unsigned long long v = pk(pp, (unsigned)(t + 2));
                FS(&g_pbF[((size_t)fb + w) * NSLOT + sA], v);
                AS(&g_pb [((size_t)fb + w) * NSLOT + sA], v);
            }
        }
        // no trailing barrier: next P0 writes hh only after its own barrier
    }

    // ---- epilogue: gather h_T (safe poll), final slot-63 update, dump ----
    {
        const unsigned long long* hb = &g_hb[(size_t)b * D_SZ + 2 * tid];
        unsigned long long v0, v1;
        const unsigned tgF = (unsigned)(T_SZ + 1);
        for (;;) {
            v0 = AL(hb); v1 = AL(hb + 1);
            if ((unsigned)(v0 >> 32) == tgF && (unsigned)(v1 >> 32) == tgF) break;
            __builtin_amdgcn_s_sleep(1);
        }
        hh[2 * tid]     = lo(v0);
        hh[2 * tid + 1] = lo(v1);
    }
    __syncthreads();
    {
        float v0 = 0.f, v1 = 0.f;
        const float* wwA = W_w + (size_t)(R0 + g16)      * D_SZ + 4 * sj;
        const float* wwB = W_w + (size_t)(R0 + g16 + 16) * D_SZ + 4 * sj;
        #pragma unroll
        for (int i = 0; i < 8; ++i) {
            float4 hr = *(const float4*)&hh[4 * sj + 64 * i];
            float4 b0 = *(const float4*)(wwA + 64 * i);
            float4 b1 = *(const float4*)(wwB + 64 * i);
            v0 = fmaf(b0.x, hr.x, v0); v0 = fmaf(b0.y, hr.y, v0);
            v0 = fmaf(b0.z, hr.z, v0); v0 = fmaf(b0.w, hr.w, v0);
            v1 = fmaf(b1.x, hr.x, v1); v1 = fmaf(b1.y, hr.y, v1);
            v1 = fmaf(b1.z, hr.z, v1); v1 = fmaf(b1.w, hr.w, v1);
        }
        #pragma unroll
        for (int o = 1; o <= 8; o <<= 1) { v0 += __shfl_xor(v0, o); v1 += __shfl_xor(v1, o); }
        if (sj == 0) { tp[63][g16] = v0; tp[63][g16 + 16] = v1; }
    }
    __syncthreads();
    float* tout = out + (size_t)B_SZ * T_SZ * D_SZ + (size_t)b * NSLOT * D_SZ;
    for (int i = tid; i < NSLOT * RPW; i += 256) {
        const int s = i >> 5, j = i & 31;
        tout[(size_t)s * D_SZ + R0 + j] = tp[s][j];
    }
    if (w == 0) {
        float* lout = out + (size_t)B_SZ * T_SZ * D_SZ
                          + (size_t)B_SZ * NSLOT * D_SZ + (size_t)b * D_SZ;
        for (int i = tid; i < D_SZ; i += 256) lout[i] = hh[i];
    }
}

// ---------------------------------------------------------------------------
extern "C" void kernel_launch(void* const* d_in, const int* in_sizes, int n_in,
                              void* d_out, int out_size, void* d_ws, size_t ws_size,
                              hipStream_t stream)
{
    const float* x_seq   = (const float*)d_in[0];
    const float* h_tape  = (const float*)d_in[1];
    const float* h_work  = (const float*)d_in[2];
    const float* W_h     = (const float*)d_in[3];
    const float* W_x     = (const float*)d_in[4];
    const float* b_h     = (const float*)d_in[5];
    const float* W_write = (const float*)d_in[6];
    float* out = (float*)d_out;

    dim3 g1(T_SZ * B_SZ / 64, D_SZ / 64);
    xw_gemm_kernel<<<g1, 256, 0, stream>>>(x_seq, W_x, b_h, out);

    recurrence_mw<<<B_SZ * NW, 256, 0, stream>>>(h_tape, h_work, W_h, W_write, out);
}

// Round 13
// 15953.062 us; speedup vs baseline: 1.5714x; 1.3673x over previous
//
#include <hip/hip_runtime.h>
#include <cstddef>

#define B_SZ   16
#define T_SZ   4096
#define D_SZ   512
#define NSLOT  64
#define NW     16          // workgroups (d-slices) per batch
#define RPW    32          // rows per WG slice (D_SZ / NW)
#define TP     36          // LDS tape row stride (floats, padded)
#define SCALE  0.044194173824159216f   // 1/sqrt(512)

// ---- cross-WG exchange: self-tagged (float,tag) 8B pairs. Consumer polls the
// ---- datum itself until tag==t+1 — no flags, no vmcnt, no fences. Producers
// ---- zero their own slots at kernel start (same-thread ordering) so tag
// ---- history per address is {0,1,...}, making equality polls replay-safe.
__device__ __align__(8) unsigned long long g_ps2[B_SZ * NW * NSLOT]; // partial scores
__device__ __align__(8) unsigned long long g_hx2[B_SZ * D_SZ];      // h_new by [b][d]

#define AL(p)    __hip_atomic_load((p),  __ATOMIC_RELAXED, __HIP_MEMORY_SCOPE_AGENT)
#define AS(p,v)  __hip_atomic_store((p), (v), __ATOMIC_RELAXED, __HIP_MEMORY_SCOPE_AGENT)

__device__ __forceinline__ unsigned long long pk(float v, unsigned tag) {
    return ((unsigned long long)tag << 32) | (unsigned long long)__float_as_uint(v);
}

// ---------------------------------------------------------------------------
// Kernel 1: xw[b][t][d] = x[b][t][:] . W_x[d][:] + b_h[d]  -> h_work_out region
// ---------------------------------------------------------------------------
__global__ __launch_bounds__(256)
void xw_gemm_kernel(const float* __restrict__ X, const float* __restrict__ Wx,
                    const float* __restrict__ bh, float* __restrict__ out)
{
    __shared__ float As[16][68];
    __shared__ float Bs[16][68];
    const int m0 = blockIdx.x * 64;
    const int n0 = blockIdx.y * 64;
    const int tid = threadIdx.x;
    const int tr = tid >> 4, tc = tid & 15;
    const int lrow = tid >> 2;
    const int lkk  = (tid & 3) * 4;

    float acc[4][4] = {};

    for (int k0 = 0; k0 < D_SZ; k0 += 16) {
        float4 av = *(const float4*)(X  + (size_t)(m0 + lrow) * D_SZ + k0 + lkk);
        float4 bv = *(const float4*)(Wx + (size_t)(n0 + lrow) * D_SZ + k0 + lkk);
        As[lkk+0][lrow] = av.x; As[lkk+1][lrow] = av.y;
        As[lkk+2][lrow] = av.z; As[lkk+3][lrow] = av.w;
        Bs[lkk+0][lrow] = bv.x; Bs[lkk+1][lrow] = bv.y;
        Bs[lkk+2][lrow] = bv.z; Bs[lkk+3][lrow] = bv.w;
        __syncthreads();
        #pragma unroll
        for (int kk = 0; kk < 16; ++kk) {
            float a[4], b[4];
            #pragma unroll
            for (int i = 0; i < 4; ++i) a[i] = As[kk][tr*4+i];
            #pragma unroll
            for (int j = 0; j < 4; ++j) b[j] = Bs[kk][tc*4+j];
            #pragma unroll
            for (int i = 0; i < 4; ++i)
                #pragma unroll
                for (int j = 0; j < 4; ++j)
                    acc[i][j] = fmaf(a[i], b[j], acc[i][j]);
        }
        __syncthreads();
    }
    #pragma unroll
    for (int i = 0; i < 4; ++i) {
        const int m = m0 + tr*4 + i;
        const int n = n0 + tc*4;
        float4 o;
        o.x = acc[i][0] + bh[n+0];
        o.y = acc[i][1] + bh[n+1];
        o.z = acc[i][2] + bh[n+2];
        o.w = acc[i][3] + bh[n+3];
        *(float4*)(out + (size_t)m * D_SZ + n) = o;
    }
}

// ---------------------------------------------------------------------------
// Kernel 2: d-sliced recurrence, self-tagged-pair sync, weights streamed from
// L2 per step (compiler in-loop loads; hand-hoisting spills — R9/R10).
// ---------------------------------------------------------------------------
__global__ __launch_bounds__(256, 1)
void recurrence_mw(const float* __restrict__ tape0, const float* __restrict__ h0,
                   const float* __restrict__ W_h, const float* __restrict__ W_w,
                   float* __restrict__ out)
{
    __shared__ float tp[NSLOT][TP];    // 9,216 B (tape d-slice)
    __shared__ float hh[D_SZ];         // 2,048 B
    __shared__ float ps_l[NSLOT];
    __shared__ float attn[NSLOT];
    __shared__ float zmv[RPW];
    __shared__ float rp8[8][RPW];

    const int blk = blockIdx.x;
    const int xcd = blk & 7;
    const int jj0 = blk >> 3;
    const int b   = xcd * 2 + (jj0 & 1);
    const int w   = jj0 >> 1;
    const int R0  = w * RPW;
    const int tid = threadIdx.x;
    const int fb  = b * NW;
    const int g16 = tid >> 4, sj = tid & 15;  // matvec layout: 16 lanes per row

    // ---- zero own pair slots (replay safety; 0 never matches tag>=1) ----
    if (tid < NSLOT) AS(&g_ps2[(size_t)(fb + w) * NSLOT + tid], 0ULL);
    if (tid < RPW)   AS(&g_hx2[(size_t)b * D_SZ + R0 + tid], 0ULL);

    // ---- weight slices into REGISTERS (once) ----
    float4 wh0[8], wh1[8], ww0[8], ww1[8];
    {
        const float* a0 = W_h + (size_t)(R0 + g16)      * D_SZ + 4 * sj;
        const float* a1 = W_h + (size_t)(R0 + g16 + 16) * D_SZ + 4 * sj;
        const float* b0 = W_w + (size_t)(R0 + g16)      * D_SZ + 4 * sj;
        const float* b1 = W_w + (size_t)(R0 + g16 + 16) * D_SZ + 4 * sj;
        #pragma unroll
        for (int i = 0; i < 8; ++i) {
            wh0[i] = *(const float4*)(a0 + 64 * i);
            wh1[i] = *(const float4*)(a1 + 64 * i);
            ww0[i] = *(const float4*)(b0 + 64 * i);
            ww1[i] = *(const float4*)(b1 + 64 * i);
        }
    }

    // ---- tape slice + h into LDS ----
    for (int i = tid; i < NSLOT * RPW; i += 256) {
        const int s = i >> 5, jc = i & 31;
        tp[s][jc] = tape0[((size_t)b * NSLOT + s) * D_SZ + R0 + jc];
    }
    for (int i = tid; i < D_SZ; i += 256) hh[i] = h0[(size_t)b * D_SZ + i];
    __syncthreads();

    float* outb = out + (size_t)b * T_SZ * D_SZ;

    const int sA = tid >> 2, qA = tid & 3;    // 4 threads per slot (scores)
    const int jB = tid & 31, sg = tid >> 5;   // read-partials: 8 slot-groups

    for (int t = 0; t < T_SZ; ++t) {
        const unsigned tg = (unsigned)(t + 1);
        float xwv = 0.f;
        if (tid < RPW) xwv = outb[(size_t)t * D_SZ + R0 + tid];

        // ---- A1: local partial scores over our 32 d's ----
        {
            float4 t0 = *(const float4*)&tp[sA][qA * 8];
            float4 t1 = *(const float4*)&tp[sA][qA * 8 + 4];
            float4 ha = *(const float4*)&hh[R0 + qA * 8];
            float4 hb = *(const float4*)&hh[R0 + qA * 8 + 4];
            float acc = t0.x*ha.x + t0.y*ha.y + t0.z*ha.z + t0.w*ha.w
                      + t1.x*hb.x + t1.y*hb.y + t1.z*hb.z + t1.w*hb.w;
            acc += __shfl_xor(acc, 1);
            acc += __shfl_xor(acc, 2);
            if (qA == 0) ps_l[sA] = acc;
        }
        __syncthreads();

        // ---- A2: publish tagged partial scores ----
        if (tid < NSLOT)
            AS(&g_ps2[(size_t)(fb + w) * NSLOT + tid], pk(ps_l[tid], tg));

        // ---- B2: zm = W_h . h from REGISTERS — overlaps score propagation ----
        {
            float a0 = 0.f, a1 = 0.f;
            #pragma unroll
            for (int i = 0; i < 8; ++i) {
                float4 hr = *(const float4*)&hh[4 * sj + 64 * i];
                a0 = fmaf(wh0[i].x, hr.x, a0);
                a0 = fmaf(wh0[i].y, hr.y, a0);
                a0 = fmaf(wh0[i].z, hr.z, a0);
                a0 = fmaf(wh0[i].w, hr.w, a0);
                a1 = fmaf(wh1[i].x, hr.x, a1);
                a1 = fmaf(wh1[i].y, hr.y, a1);
                a1 = fmaf(wh1[i].z, hr.z, a1);
                a1 = fmaf(wh1[i].w, hr.w, a1);
            }
            a0 += __shfl_xor(a0, 1); a1 += __shfl_xor(a1, 1);
            a0 += __shfl_xor(a0, 2); a1 += __shfl_xor(a1, 2);
            a0 += __shfl_xor(a0, 4); a1 += __shfl_xor(a1, 4);
            a0 += __shfl_xor(a0, 8); a1 += __shfl_xor(a1, 8);
            if (sj == 0) { zmv[g16] = a0; zmv[g16 + 16] = a1; }
        }

        // ---- poll 4 score pairs (w' = 4*qA..4*qA+3, slot sA); sum on match ----
        {
            const unsigned long long* pp = &g_ps2[(size_t)(fb + qA * 4) * NSLOT + sA];
            unsigned long long v0, v1, v2, v3;
            for (;;) {
                v0 = AL(pp + 0 * NSLOT); v1 = AL(pp + 1 * NSLOT);
                v2 = AL(pp + 2 * NSLOT); v3 = AL(pp + 3 * NSLOT);
                if ((unsigned)(v0 >> 32) == tg && (unsigned)(v1 >> 32) == tg &&
                    (unsigned)(v2 >> 32) == tg && (unsigned)(v3 >> 32) == tg) break;
                __builtin_amdgcn_s_sleep(1);
            }
            float acc = __uint_as_float((unsigned)v0) + __uint_as_float((unsigned)v1)
                      + __uint_as_float((unsigned)v2) + __uint_as_float((unsigned)v3);
            acc += __shfl_xor(acc, 1);
            acc += __shfl_xor(acc, 2);
            if (qA == 0) ps_l[sA] = acc * SCALE;
        }
        __syncthreads();

        // ---- softmax over 64 slots (wave 0) ----
        if (tid < 64) {
            const float v = ps_l[tid];
            float m = v;
            #pragma unroll
            for (int o = 32; o; o >>= 1) m = fmaxf(m, __shfl_xor(m, o));
            const float e = __expf(v - m);
            float s = e;
            #pragma unroll
            for (int o = 32; o; o >>= 1) s += __shfl_xor(s, o);
            attn[tid] = e / s;
        }
        __syncthreads();

        // ---- B: read partials over our d-slice ----
        {
            float acc = 0.f;
            #pragma unroll
            for (int s8 = 0; s8 < 8; ++s8)
                acc = fmaf(attn[sg * 8 + s8], tp[sg * 8 + s8][jB], acc);
            rp8[sg][jB] = acc;
        }
        __syncthreads();

        // ---- C: h_new own rows; publish tagged pairs ----
        if (tid < RPW) {
            const float rr = rp8[0][tid] + rp8[1][tid] + rp8[2][tid] + rp8[3][tid]
                           + rp8[4][tid] + rp8[5][tid] + rp8[6][tid] + rp8[7][tid];
            const float v = tanhf(zmv[tid] + rr + xwv);
            outb[(size_t)t * D_SZ + R0 + tid] = v;
            AS(&g_hx2[(size_t)b * D_SZ + R0 + tid], pk(v, tg));
        }

        // ---- C2: poll own two h pairs, fill hh ----
        {
            const int d0 = tid * 2;
            const unsigned long long* hp = &g_hx2[(size_t)b * D_SZ + d0];
            unsigned long long v0, v1;
            for (;;) {
                v0 = AL(hp); v1 = AL(hp + 1);
                if ((unsigned)(v0 >> 32) == tg && (unsigned)(v1 >> 32) == tg) break;
                __builtin_amdgcn_s_sleep(1);
            }
            hh[d0]     = __uint_as_float((unsigned)v0);
            hh[d0 + 1] = __uint_as_float((unsigned)v1);
        }
        __syncthreads();

        // ---- D: w_vec rows from REGISTER weights -> tape slot ----
        {
            const int slot = t & (NSLOT - 1);
            float a0 = 0.f, a1 = 0.f;
            #pragma unroll
            for (int i = 0; i < 8; ++i) {
                float4 hr = *(const float4*)&hh[4 * sj + 64 * i];
                a0 = fmaf(ww0[i].x, hr.x, a0);
                a0 = fmaf(ww0[i].y, hr.y, a0);
                a0 = fmaf(ww0[i].z, hr.z, a0);
                a0 = fmaf(ww0[i].w, hr.w, a0);
                a1 = fmaf(ww1[i].x, hr.x, a1);
                a1 = fmaf(ww1[i].y, hr.y, a1);
                a1 = fmaf(ww1[i].z, hr.z, a1);
                a1 = fmaf(ww1[i].w, hr.w, a1);
            }
            a0 += __shfl_xor(a0, 1); a1 += __shfl_xor(a1, 1);
            a0 += __shfl_xor(a0, 2); a1 += __shfl_xor(a1, 2);
            a0 += __shfl_xor(a0, 4); a1 += __shfl_xor(a1, 4);
            a0 += __shfl_xor(a0, 8); a1 += __shfl_xor(a1, 8);
            if (sj == 0) {
                tp[slot][g16]      = a0;
                tp[slot][g16 + 16] = a1;
            }
        }
        __syncthreads();
    }

    // ---- epilogue: tape slice + last-h slice ----
    float* tout = out + (size_t)B_SZ * T_SZ * D_SZ + (size_t)b * NSLOT * D_SZ;
    for (int i = tid; i < NSLOT * RPW; i += 256) {
        const int s = i >> 5, jc = i & 31;
        tout[(size_t)s * D_SZ + R0 + jc] = tp[s][jc];
    }
    if (tid < RPW) {
        float* lout = out + (size_t)B_SZ * T_SZ * D_SZ
                          + (size_t)B_SZ * NSLOT * D_SZ + (size_t)b * D_SZ;
        lout[R0 + tid] = hh[R0 + tid];
    }
}

// ---------------------------------------------------------------------------
extern "C" void kernel_launch(void* const* d_in, const int* in_sizes, int n_in,
                              void* d_out, int out_size, void* d_ws, size_t ws_size,
                              hipStream_t stream)
{
    const float* x_seq   = (const float*)d_in[0];
    const float* h_tape  = (const float*)d_in[1];
    const float* h_work  = (const float*)d_in[2];
    const float* W_h     = (const float*)d_in[3];
    const float* W_x     = (const float*)d_in[4];
    const float* b_h     = (const float*)d_in[5];
    const float* W_write = (const float*)d_in[6];
    float* out = (float*)d_out;

    dim3 g1(T_SZ * B_SZ / 64, D_SZ / 64);
    xw_gemm_kernel<<<g1, 256, 0, stream>>>(x_seq, W_x, b_h, out);

    recurrence_mw<<<B_SZ * NW, 256, 0, stream>>>(h_tape, h_work, W_h, W_write, out);
}